// Round 1
// baseline (880.315 us; speedup 1.0000x reference)
//
#include <hip/hip_runtime.h>
#include <hip/hip_bf16.h>

#define B_ 4
#define T_ 4096
#define C_ 768
#define H_ 64

// ---------------------------------------------------------------------------
// QKV projection: q/k/v = x @ W{q,k,v}.  [16384 x 768] * [768 x 64]
// 512 blocks x 256 threads. Each block: 32 rows (8 per wave, lane = h).
// W tiles (64 x 64 x 3 fp32 = 48 KB) staged in LDS, reused by all rows.
// ---------------------------------------------------------------------------
__global__ __launch_bounds__(256) void qkv_proj(
    const float* __restrict__ x,
    const float* __restrict__ Wk,
    const float* __restrict__ Wq,
    const float* __restrict__ Wv,
    float* __restrict__ qo,
    float* __restrict__ ko,
    float* __restrict__ vo)
{
    __shared__ float Wqs[64][64];
    __shared__ float Wks[64][64];
    __shared__ float Wvs[64][64];

    const int tid  = threadIdx.x;
    const int lane = tid & 63;
    const int wid  = tid >> 6;
    const int rowBase = blockIdx.x * 32 + wid * 8;

    float aq[8], ak[8], av[8];
#pragma unroll
    for (int u = 0; u < 8; ++u) { aq[u] = 0.f; ak[u] = 0.f; av[u] = 0.f; }

    for (int c0 = 0; c0 < C_; c0 += 64) {
        __syncthreads();
        for (int i = tid; i < 64 * 64; i += 256) {
            Wqs[i >> 6][i & 63] = Wq[(size_t)c0 * H_ + i];
            Wks[i >> 6][i & 63] = Wk[(size_t)c0 * H_ + i];
            Wvs[i >> 6][i & 63] = Wv[(size_t)c0 * H_ + i];
        }
        __syncthreads();

        for (int cc = 0; cc < 64; cc += 4) {
            float4 xv[8];
#pragma unroll
            for (int u = 0; u < 8; ++u)
                xv[u] = *reinterpret_cast<const float4*>(
                    &x[(size_t)(rowBase + u) * C_ + c0 + cc]);
#pragma unroll
            for (int q4 = 0; q4 < 4; ++q4) {
                const float wq = Wqs[cc + q4][lane];
                const float wk = Wks[cc + q4][lane];
                const float wv = Wvs[cc + q4][lane];
#pragma unroll
                for (int u = 0; u < 8; ++u) {
                    const float xs = (&xv[u].x)[q4];
                    aq[u] += xs * wq;
                    ak[u] += xs * wk;
                    av[u] += xs * wv;
                }
            }
        }
    }

#pragma unroll
    for (int u = 0; u < 8; ++u) {
        const size_t idx = (size_t)(rowBase + u) * H_ + lane;
        qo[idx] = aq[u];
        ko[idx] = ak[u];
        vo[idx] = av[u];
    }
}

// ---------------------------------------------------------------------------
// Causal flash attention (fp32, online softmax).
// Grid: 256 blocks = 4 batches x 64 pair-slots. Block handles q-tiles
// pi and 127-pi (32 rows each) -> balanced ~65 kv-tiles (of 64) per block.
// Threads: 256. r = tid&31 (q-row), g = tid>>5 (8 h/score columns each).
// ---------------------------------------------------------------------------
__global__ __launch_bounds__(256) void attn(
    const float* __restrict__ q,
    const float* __restrict__ k,
    const float* __restrict__ v,
    float* __restrict__ out)
{
    __shared__ float Qs[32][65];
    __shared__ float Ks[64][65];
    __shared__ float Vs[64][65];
    __shared__ float Ss[32][65];

    const int b   = blockIdx.x >> 6;
    const int pi  = blockIdx.x & 63;
    const int tid = threadIdx.x;
    const int r   = tid & 31;
    const int g   = tid >> 5;   // 0..7
    const size_t bt0 = (size_t)b * T_;
    const float scale = 0.03608439182435161f;  // 768^-0.5

    for (int pp = 0; pp < 2; ++pp) {
        const int qt = pp ? (127 - pi) : pi;
        const int qb = qt * 32;

        __syncthreads();  // guard LDS reuse across q-tiles
        for (int i = tid; i < 32 * 64; i += 256)
            Qs[i >> 6][i & 63] = q[(bt0 + qb + (i >> 6)) * H_ + (i & 63)];

        float acc[8];
#pragma unroll
        for (int j = 0; j < 8; ++j) acc[j] = 0.f;
        float m = -3.0e38f, l = 0.f;

        const int nk = ((qb + 31) >> 6) + 1;
        for (int kt = 0; kt < nk; ++kt) {
            const int kb = kt << 6;
            __syncthreads();  // prior PV done before restaging K/V
            for (int i = tid; i < 64 * 64; i += 256) {
                const int row = i >> 6, c = i & 63;
                const size_t gidx = (bt0 + kb + row) * H_ + c;
                Ks[row][c] = k[gidx];
                Vs[row][c] = v[gidx];
            }
            __syncthreads();

            // ---- scores: S[r][g*8+j] = Q[r] . K[g*8+j]
            float s[8];
#pragma unroll
            for (int j = 0; j < 8; ++j) s[j] = 0.f;
            for (int c = 0; c < 64; ++c) {
                const float qv = Qs[r][c];
#pragma unroll
                for (int j = 0; j < 8; ++j) s[j] += qv * Ks[g * 8 + j][c];
            }
#pragma unroll
            for (int j = 0; j < 8; ++j) {
                float sv = s[j] * scale;
                if (kb + g * 8 + j > qb + r) sv = -3.0e38f;  // causal mask
                Ss[r][g * 8 + j] = sv;
            }
            __syncthreads();

            // ---- online softmax row stats (redundant across the 8 g-threads)
            float tmax = -3.0e38f;
            for (int c = 0; c < 64; ++c) tmax = fmaxf(tmax, Ss[r][c]);
            const float mnew = fmaxf(m, tmax);
            const float sf   = __expf(m - mnew);
            float lsum = 0.f;
            for (int c = 0; c < 64; ++c) lsum += __expf(Ss[r][c] - mnew);
            __syncthreads();  // all reads of S done before in-place P write

            if (tid < 64) {   // first wave writes P = exp(S - mnew) in place
                const int rr = tid & 31, hh = tid >> 5;
                for (int c = 0; c < 32; ++c) {
                    const int col = hh * 32 + c;
                    Ss[rr][col] = __expf(Ss[rr][col] - mnew);
                }
            }
            __syncthreads();

            // ---- PV accumulate
#pragma unroll
            for (int j = 0; j < 8; ++j) acc[j] *= sf;
            for (int s2 = 0; s2 < 64; ++s2) {
                const float p = Ss[r][s2];
#pragma unroll
                for (int j = 0; j < 8; ++j) acc[j] += p * Vs[s2][g * 8 + j];
            }
            m = mnew;
            l = l * sf + lsum;
        }

#pragma unroll
        for (int j = 0; j < 8; ++j)
            out[(bt0 + qb + r) * H_ + g * 8 + j] = acc[j] / l;
    }
}

extern "C" void kernel_launch(void* const* d_in, const int* in_sizes, int n_in,
                              void* d_out, int out_size, void* d_ws, size_t ws_size,
                              hipStream_t stream) {
    const float* x  = (const float*)d_in[0];
    const float* Wk = (const float*)d_in[1];
    const float* Wq = (const float*)d_in[2];
    const float* Wv = (const float*)d_in[3];
    float* out = (float*)d_out;

    float* qws = (float*)d_ws;                       // [B*T][H]
    float* kws = qws + (size_t)B_ * T_ * H_;
    float* vws = kws + (size_t)B_ * T_ * H_;

    qkv_proj<<<dim3(512), dim3(256), 0, stream>>>(x, Wk, Wq, Wv, qws, kws, vws);
    attn<<<dim3(256), dim3(256), 0, stream>>>(qws, kws, vws, out);
}

// Round 2
// 200.854 us; speedup vs baseline: 4.3829x; 4.3829x over previous
//
#include <hip/hip_runtime.h>

typedef _Float16 f16x8 __attribute__((ext_vector_type(8)));
typedef float    f32x4 __attribute__((ext_vector_type(4)));

#define B_ 4
#define T_ 4096
#define C_ 768
#define H_ 64
#define SCALE 0.03608439182435161f   // 768^-0.5

// ---------------------------------------------------------------------------
// QKV projection -> f16 outputs. q pre-scaled by 768^-0.5. v written
// TRANSPOSED: vt[h][b*T+s] so attention can stage V with contiguous reads.
// 512 blocks x 256 threads, 32 rows/block.
// ---------------------------------------------------------------------------
__global__ __launch_bounds__(256) void qkv_proj(
    const float* __restrict__ x,
    const float* __restrict__ Wk,
    const float* __restrict__ Wq,
    const float* __restrict__ Wv,
    _Float16* __restrict__ qo,
    _Float16* __restrict__ ko,
    _Float16* __restrict__ vt)
{
    __shared__ float Wqs[64][64];
    __shared__ float Wks[64][64];
    __shared__ float Wvs[64][64];
    __shared__ _Float16 avs[32][72];

    const int tid  = threadIdx.x;
    const int lane = tid & 63;
    const int wid  = tid >> 6;
    const int rowBase = blockIdx.x * 32 + wid * 8;

    float aq[8], ak[8], av[8];
#pragma unroll
    for (int u = 0; u < 8; ++u) { aq[u] = 0.f; ak[u] = 0.f; av[u] = 0.f; }

    for (int c0 = 0; c0 < C_; c0 += 64) {
        __syncthreads();
        for (int i = tid; i < 64 * 64; i += 256) {
            Wqs[i >> 6][i & 63] = Wq[(size_t)c0 * H_ + i];
            Wks[i >> 6][i & 63] = Wk[(size_t)c0 * H_ + i];
            Wvs[i >> 6][i & 63] = Wv[(size_t)c0 * H_ + i];
        }
        __syncthreads();

        for (int cc = 0; cc < 64; cc += 4) {
            float4 xv[8];
#pragma unroll
            for (int u = 0; u < 8; ++u)
                xv[u] = *reinterpret_cast<const float4*>(
                    &x[(size_t)(rowBase + u) * C_ + c0 + cc]);
#pragma unroll
            for (int q4 = 0; q4 < 4; ++q4) {
                const float wq = Wqs[cc + q4][lane];
                const float wk = Wks[cc + q4][lane];
                const float wv = Wvs[cc + q4][lane];
#pragma unroll
                for (int u = 0; u < 8; ++u) {
                    const float xs = (&xv[u].x)[q4];
                    aq[u] += xs * wq;
                    ak[u] += xs * wk;
                    av[u] += xs * wv;
                }
            }
        }
    }

#pragma unroll
    for (int u = 0; u < 8; ++u) {
        const size_t idx = (size_t)(rowBase + u) * H_ + lane;
        qo[idx] = (_Float16)(aq[u] * SCALE);
        ko[idx] = (_Float16)ak[u];
        avs[wid * 8 + u][lane] = (_Float16)av[u];
    }
    __syncthreads();

    // transpose-store v: thread t -> h = t>>2, 8 s-values
    const int h  = tid >> 2;
    const int sb = tid & 3;
    f16x8 vv;
#pragma unroll
    for (int j = 0; j < 8; ++j) vv[j] = avs[sb * 8 + j][h];
    *(f16x8*)&vt[(size_t)h * (B_ * T_) + blockIdx.x * 32 + sb * 8] = vv;
}

// ---------------------------------------------------------------------------
// MFMA causal flash attention.
// Grid 512 = 4 batches x 128 q-tiles (32 rows each), qt assigned descending
// so heavy blocks dispatch first. 4 waves: qw = wid&1 (16 q-rows each),
// ks = wid>>1 (causal kv-range split in half); halves merged in LDS at end.
// mfma_f32_16x16x32_f16 layouts: A row=lane&15,k=(lane>>4)*8+i; B col=lane&15,
// same k; D row=(lane>>4)*4+r, col=lane&15.
// ---------------------------------------------------------------------------
__global__ __launch_bounds__(256) void attn(
    const _Float16* __restrict__ qh,
    const _Float16* __restrict__ kh,
    const _Float16* __restrict__ vt,
    float* __restrict__ out)
{
    __shared__ _Float16 Ks[2][64][72];   // [ks][s][h], stride 72 keeps b128 16B-aligned
    __shared__ _Float16 Vs[2][64][72];   // [ks][h][s_local]
    __shared__ _Float16 Ps[4][16][72];   // per-wave P scratch [q][s_local]
    __shared__ float    Om[2][16][68];   // merge: O of ks=1 half
    __shared__ float    Ml[2][2][16];    // merge: m,l of ks=1 half

    const int b   = blockIdx.x >> 7;
    const int qt  = 127 - (blockIdx.x & 127);   // heavy first
    const int qb  = qt << 5;
    const int tid = threadIdx.x;
    const int lane = tid & 63;
    const int wid  = tid >> 6;
    const int qw   = wid & 1;
    const int ks   = wid >> 1;
    const size_t bt0 = (size_t)b * T_;
    const int l15 = lane & 15;
    const int l4  = lane >> 4;

    // Q fragments (A operand), q already scaled
    const size_t qrow = bt0 + qb + qw * 16 + l15;
    const f16x8 qf0 = *(const f16x8*)&qh[qrow * H_ + l4 * 8];
    const f16x8 qf1 = *(const f16x8*)&qh[qrow * H_ + 32 + l4 * 8];

    f32x4 O[4];
#pragma unroll
    for (int ht = 0; ht < 4; ++ht) O[ht] = (f32x4){0.f, 0.f, 0.f, 0.f};
    float m[4] = {-1e30f, -1e30f, -1e30f, -1e30f};
    float l[4] = {0.f, 0.f, 0.f, 0.f};

    const int NT  = (qb >> 6) + 1;       // kv tiles covering [0, qb+32)
    const int NT1 = (NT + 1) >> 1;       // ks=0 tiles [0,NT1), ks=1 [NT1,NT)
    const int t0  = ks ? NT1 : 0;
    const int tn  = ks ? (NT - NT1) : NT1;
    const int hht = tid & 127;           // thread id within kv-half

    for (int it = 0; it < NT1; ++it) {
        const int kb = (t0 + it) << 6;
        __syncthreads();
        if (it < tn) {
            // stage K [s][h] and V [h][s_local] for this half
#pragma unroll
            for (int i = 0; i < 4; ++i) {
                const int row = i * 16 + (hht >> 3);
                const int col = (hht & 7) * 8;
                *(f16x8*)&Ks[ks][row][col] =
                    *(const f16x8*)&kh[(bt0 + kb + row) * H_ + col];
                *(f16x8*)&Vs[ks][row][col] =
                    *(const f16x8*)&vt[(size_t)row * (B_ * T_) + bt0 + kb + col];
            }
        }
        __syncthreads();
        if (it < tn) {
            // ---- S = Q K^T (scaled)
            f32x4 sfr[4];
#pragma unroll
            for (int nt = 0; nt < 4; ++nt) {
                const f16x8 kf0 = *(const f16x8*)&Ks[ks][nt * 16 + l15][l4 * 8];
                const f16x8 kf1 = *(const f16x8*)&Ks[ks][nt * 16 + l15][32 + l4 * 8];
                f32x4 z = (f32x4){0.f, 0.f, 0.f, 0.f};
                z = __builtin_amdgcn_mfma_f32_16x16x32_f16(qf0, kf0, z, 0, 0, 0);
                sfr[nt] = __builtin_amdgcn_mfma_f32_16x16x32_f16(qf1, kf1, z, 0, 0, 0);
            }
            // ---- causal mask
            const int qpos = qb + qw * 16 + l4 * 4;
#pragma unroll
            for (int nt = 0; nt < 4; ++nt) {
                const int cpos = kb + nt * 16 + l15;
#pragma unroll
                for (int r = 0; r < 4; ++r)
                    if (cpos > qpos + r) sfr[nt][r] = -1e30f;
            }
            // ---- online softmax (wave-parallel, rows live in 16-lane groups)
            float sf[4];
            float p[4][4];
#pragma unroll
            for (int r = 0; r < 4; ++r) {
                float mx = fmaxf(fmaxf(sfr[0][r], sfr[1][r]),
                                 fmaxf(sfr[2][r], sfr[3][r]));
                mx = fmaxf(mx, __shfl_xor(mx, 1));
                mx = fmaxf(mx, __shfl_xor(mx, 2));
                mx = fmaxf(mx, __shfl_xor(mx, 4));
                mx = fmaxf(mx, __shfl_xor(mx, 8));
                const float mn = fmaxf(m[r], mx);
                sf[r] = __expf(m[r] - mn);
                float rs = 0.f;
#pragma unroll
                for (int nt = 0; nt < 4; ++nt) {
                    p[nt][r] = __expf(sfr[nt][r] - mn);
                    rs += p[nt][r];
                }
                rs += __shfl_xor(rs, 1);
                rs += __shfl_xor(rs, 2);
                rs += __shfl_xor(rs, 4);
                rs += __shfl_xor(rs, 8);
                l[r] = l[r] * sf[r] + rs;
                m[r] = mn;
            }
            // ---- P -> LDS (D-frag layout in, A-frag layout out)
#pragma unroll
            for (int nt = 0; nt < 4; ++nt)
#pragma unroll
                for (int r = 0; r < 4; ++r)
                    Ps[wid][l4 * 4 + r][nt * 16 + l15] = (_Float16)p[nt][r];
            // ---- rescale O
#pragma unroll
            for (int ht = 0; ht < 4; ++ht)
#pragma unroll
                for (int r = 0; r < 4; ++r) O[ht][r] *= sf[r];
            // ---- PV
            const f16x8 pf0 = *(const f16x8*)&Ps[wid][l15][l4 * 8];
            const f16x8 pf1 = *(const f16x8*)&Ps[wid][l15][32 + l4 * 8];
#pragma unroll
            for (int ht = 0; ht < 4; ++ht) {
                const f16x8 vf0 = *(const f16x8*)&Vs[ks][ht * 16 + l15][l4 * 8];
                const f16x8 vf1 = *(const f16x8*)&Vs[ks][ht * 16 + l15][32 + l4 * 8];
                O[ht] = __builtin_amdgcn_mfma_f32_16x16x32_f16(pf0, vf0, O[ht], 0, 0, 0);
                O[ht] = __builtin_amdgcn_mfma_f32_16x16x32_f16(pf1, vf1, O[ht], 0, 0, 0);
            }
        }
    }

    // ---- merge the two kv-halves, write out (fp32)
    __syncthreads();
    const int row = l4 * 4;
    if (ks == 1) {
        if (l15 == 0) {
#pragma unroll
            for (int r = 0; r < 4; ++r) {
                Ml[qw][0][row + r] = m[r];
                Ml[qw][1][row + r] = l[r];
            }
        }
#pragma unroll
        for (int ht = 0; ht < 4; ++ht)
#pragma unroll
            for (int r = 0; r < 4; ++r)
                Om[qw][row + r][ht * 16 + l15] = O[ht][r];
    }
    __syncthreads();
    if (ks == 0) {
#pragma unroll
        for (int r = 0; r < 4; ++r) {
            const float m1 = Ml[qw][0][row + r];
            const float l1 = Ml[qw][1][row + r];
            const float mf = fmaxf(m[r], m1);
            const float a0 = __expf(m[r] - mf);
            const float a1 = __expf(m1 - mf);
            const float inv = 1.f / (l[r] * a0 + l1 * a1);
#pragma unroll
            for (int ht = 0; ht < 4; ++ht) {
                const float v =
                    (O[ht][r] * a0 + Om[qw][row + r][ht * 16 + l15] * a1) * inv;
                out[(bt0 + qb + qw * 16 + row + r) * H_ + ht * 16 + l15] = v;
            }
        }
    }
}

extern "C" void kernel_launch(void* const* d_in, const int* in_sizes, int n_in,
                              void* d_out, int out_size, void* d_ws, size_t ws_size,
                              hipStream_t stream) {
    const float* x  = (const float*)d_in[0];
    const float* Wk = (const float*)d_in[1];
    const float* Wq = (const float*)d_in[2];
    const float* Wv = (const float*)d_in[3];
    float* out = (float*)d_out;

    _Float16* qh = (_Float16*)d_ws;                  // [B*T][H] (scaled)
    _Float16* kh = qh + (size_t)B_ * T_ * H_;        // [B*T][H]
    _Float16* vt = kh + (size_t)B_ * T_ * H_;        // [H][B*T]

    qkv_proj<<<dim3(512), dim3(256), 0, stream>>>(x, Wk, Wq, Wv, qh, kh, vt);
    attn<<<dim3(512), dim3(256), 0, stream>>>(qh, kh, vt, out);
}

// Round 3
// 103.421 us; speedup vs baseline: 8.5119x; 1.9421x over previous
//
#include <hip/hip_runtime.h>

typedef _Float16 f16x8 __attribute__((ext_vector_type(8)));
typedef _Float16 f16x4 __attribute__((ext_vector_type(4)));
typedef float    f32x4 __attribute__((ext_vector_type(4)));

#define B_ 4
#define T_ 4096
#define C_ 768
#define H_ 64
#define SCALE 0.03608439182435161f   // 768^-0.5

// ---------------------------------------------------------------------------
// W transpose+cast: Wt f16 [192][768], rows 0-63 = Wq^T, 64-127 = Wk^T,
// 128-191 = Wv^T. 12 blocks x 256 threads, one 64-k slab each.
// ---------------------------------------------------------------------------
__global__ __launch_bounds__(256) void wt_cast(
    const float* __restrict__ Wk,
    const float* __restrict__ Wq,
    const float* __restrict__ Wv,
    _Float16* __restrict__ Wt)
{
    __shared__ float Ws[64][192];
    const int tid = threadIdx.x;
    const int k0  = blockIdx.x * 64;
    for (int i = tid; i < 64 * 64; i += 256) {
        const int r = i >> 6, c = i & 63;
        Ws[r][c]       = Wq[(size_t)(k0 + r) * H_ + c];
        Ws[r][64 + c]  = Wk[(size_t)(k0 + r) * H_ + c];
        Ws[r][128 + c] = Wv[(size_t)(k0 + r) * H_ + c];
    }
    __syncthreads();
#pragma unroll
    for (int r = 0; r < 6; ++r) {
        const int idx = tid + r * 256;
        const int n = idx >> 3, c8 = (idx & 7) * 8;
        f16x8 o;
#pragma unroll
        for (int j = 0; j < 8; ++j) o[j] = (_Float16)Ws[c8 + j][n];
        *(f16x8*)&Wt[(size_t)n * C_ + k0 + c8] = o;
    }
}

// ---------------------------------------------------------------------------
// QKV projection as MFMA GEMM: [16384 x 768] * [768 x 192].
// 512 blocks (BM=32), 256 threads = 4 waves; wave w owns 32 rows x cols
// [48w, 48w+48) (M_rep=2, N_rep=3). x staged fp32->f16 in LDS.
// Epilogue: q scaled -> qh, k -> kh, v transposed -> vt[h][s].
// ---------------------------------------------------------------------------
__global__ __launch_bounds__(256) void qkv_gemm(
    const float* __restrict__ x,
    const _Float16* __restrict__ Wt,
    _Float16* __restrict__ qh,
    _Float16* __restrict__ kh,
    _Float16* __restrict__ vt)
{
    __shared__ _Float16 Ah[32][72];
    __shared__ _Float16 Bh[192][72];

    const int tid  = threadIdx.x;
    const int lane = tid & 63;
    const int w    = tid >> 6;
    const int l15  = lane & 15;
    const int l4   = lane >> 4;
    const int mbase = blockIdx.x * 32;

    f32x4 acc[2][3];
#pragma unroll
    for (int mr = 0; mr < 2; ++mr)
#pragma unroll
        for (int j = 0; j < 3; ++j) acc[mr][j] = (f32x4){0.f, 0.f, 0.f, 0.f};

    for (int k0 = 0; k0 < C_; k0 += 64) {
        __syncthreads();
        {   // stage A: x[mbase..+32][k0..+64] -> f16
            const int row = tid >> 3;
            const int cb  = (tid & 7) * 8;
            const float* src = &x[(size_t)(mbase + row) * C_ + k0 + cb];
#pragma unroll
            for (int i = 0; i < 2; ++i) {
                const float4 xv = *(const float4*)(src + i * 4);
                f16x4 h = { (_Float16)xv.x, (_Float16)xv.y,
                            (_Float16)xv.z, (_Float16)xv.w };
                *(f16x4*)&Ah[row][cb + i * 4] = h;
            }
        }
#pragma unroll
        for (int r = 0; r < 6; ++r) {   // stage B: Wt[0..192][k0..+64]
            const int idx = tid + r * 256;
            const int n = idx >> 3, c8 = (idx & 7) * 8;
            *(f16x8*)&Bh[n][c8] = *(const f16x8*)&Wt[(size_t)n * C_ + k0 + c8];
        }
        __syncthreads();
#pragma unroll
        for (int kk = 0; kk < 2; ++kk) {
            f16x8 af0 = *(const f16x8*)&Ah[l15][kk * 32 + l4 * 8];
            f16x8 af1 = *(const f16x8*)&Ah[16 + l15][kk * 32 + l4 * 8];
#pragma unroll
            for (int j = 0; j < 3; ++j) {
                const f16x8 bf =
                    *(const f16x8*)&Bh[w * 48 + j * 16 + l15][kk * 32 + l4 * 8];
                acc[0][j] = __builtin_amdgcn_mfma_f32_16x16x32_f16(af0, bf, acc[0][j], 0, 0, 0);
                acc[1][j] = __builtin_amdgcn_mfma_f32_16x16x32_f16(af1, bf, acc[1][j], 0, 0, 0);
            }
        }
    }

#pragma unroll
    for (int mr = 0; mr < 2; ++mr) {
        const size_t row0 = mbase + mr * 16 + l4 * 4;
#pragma unroll
        for (int j = 0; j < 3; ++j) {
            const int gcol = w * 48 + j * 16;
            if (gcol < 64) {
                const int h = gcol + l15;
#pragma unroll
                for (int r = 0; r < 4; ++r)
                    qh[(row0 + r) * H_ + h] = (_Float16)(acc[mr][j][r] * SCALE);
            } else if (gcol < 128) {
                const int h = gcol - 64 + l15;
#pragma unroll
                for (int r = 0; r < 4; ++r)
                    kh[(row0 + r) * H_ + h] = (_Float16)acc[mr][j][r];
            } else {
                const int h = gcol - 128 + l15;
                f16x4 o = { (_Float16)acc[mr][j][0], (_Float16)acc[mr][j][1],
                            (_Float16)acc[mr][j][2], (_Float16)acc[mr][j][3] };
                *(f16x4*)&vt[(size_t)h * (B_ * T_) + row0] = o;
            }
        }
    }
}

// ---------------------------------------------------------------------------
// MFMA causal flash attention (unchanged from round 1).
// ---------------------------------------------------------------------------
__global__ __launch_bounds__(256) void attn(
    const _Float16* __restrict__ qh,
    const _Float16* __restrict__ kh,
    const _Float16* __restrict__ vt,
    float* __restrict__ out)
{
    __shared__ _Float16 Ks[2][64][72];
    __shared__ _Float16 Vs[2][64][72];
    __shared__ _Float16 Ps[4][16][72];
    __shared__ float    Om[2][16][68];
    __shared__ float    Ml[2][2][16];

    const int b   = blockIdx.x >> 7;
    const int qt  = 127 - (blockIdx.x & 127);
    const int qb  = qt << 5;
    const int tid = threadIdx.x;
    const int lane = tid & 63;
    const int wid  = tid >> 6;
    const int qw   = wid & 1;
    const int ks   = wid >> 1;
    const size_t bt0 = (size_t)b * T_;
    const int l15 = lane & 15;
    const int l4  = lane >> 4;

    const size_t qrow = bt0 + qb + qw * 16 + l15;
    const f16x8 qf0 = *(const f16x8*)&qh[qrow * H_ + l4 * 8];
    const f16x8 qf1 = *(const f16x8*)&qh[qrow * H_ + 32 + l4 * 8];

    f32x4 O[4];
#pragma unroll
    for (int ht = 0; ht < 4; ++ht) O[ht] = (f32x4){0.f, 0.f, 0.f, 0.f};
    float m[4] = {-1e30f, -1e30f, -1e30f, -1e30f};
    float l[4] = {0.f, 0.f, 0.f, 0.f};

    const int NT  = (qb >> 6) + 1;
    const int NT1 = (NT + 1) >> 1;
    const int t0  = ks ? NT1 : 0;
    const int tn  = ks ? (NT - NT1) : NT1;
    const int hht = tid & 127;

    for (int it = 0; it < NT1; ++it) {
        const int kb = (t0 + it) << 6;
        __syncthreads();
        if (it < tn) {
#pragma unroll
            for (int i = 0; i < 4; ++i) {
                const int row = i * 16 + (hht >> 3);
                const int col = (hht & 7) * 8;
                *(f16x8*)&Ks[ks][row][col] =
                    *(const f16x8*)&kh[(bt0 + kb + row) * H_ + col];
                *(f16x8*)&Vs[ks][row][col] =
                    *(const f16x8*)&vt[(size_t)row * (B_ * T_) + bt0 + kb + col];
            }
        }
        __syncthreads();
        if (it < tn) {
            f32x4 sfr[4];
#pragma unroll
            for (int nt = 0; nt < 4; ++nt) {
                const f16x8 kf0 = *(const f16x8*)&Ks[ks][nt * 16 + l15][l4 * 8];
                const f16x8 kf1 = *(const f16x8*)&Ks[ks][nt * 16 + l15][32 + l4 * 8];
                f32x4 z = (f32x4){0.f, 0.f, 0.f, 0.f};
                z = __builtin_amdgcn_mfma_f32_16x16x32_f16(qf0, kf0, z, 0, 0, 0);
                sfr[nt] = __builtin_amdgcn_mfma_f32_16x16x32_f16(qf1, kf1, z, 0, 0, 0);
            }
            const int qpos = qb + qw * 16 + l4 * 4;
#pragma unroll
            for (int nt = 0; nt < 4; ++nt) {
                const int cpos = kb + nt * 16 + l15;
#pragma unroll
                for (int r = 0; r < 4; ++r)
                    if (cpos > qpos + r) sfr[nt][r] = -1e30f;
            }
            float sf[4];
            float p[4][4];
#pragma unroll
            for (int r = 0; r < 4; ++r) {
                float mx = fmaxf(fmaxf(sfr[0][r], sfr[1][r]),
                                 fmaxf(sfr[2][r], sfr[3][r]));
                mx = fmaxf(mx, __shfl_xor(mx, 1));
                mx = fmaxf(mx, __shfl_xor(mx, 2));
                mx = fmaxf(mx, __shfl_xor(mx, 4));
                mx = fmaxf(mx, __shfl_xor(mx, 8));
                const float mn = fmaxf(m[r], mx);
                sf[r] = __expf(m[r] - mn);
                float rs = 0.f;
#pragma unroll
                for (int nt = 0; nt < 4; ++nt) {
                    p[nt][r] = __expf(sfr[nt][r] - mn);
                    rs += p[nt][r];
                }
                rs += __shfl_xor(rs, 1);
                rs += __shfl_xor(rs, 2);
                rs += __shfl_xor(rs, 4);
                rs += __shfl_xor(rs, 8);
                l[r] = l[r] * sf[r] + rs;
                m[r] = mn;
            }
#pragma unroll
            for (int nt = 0; nt < 4; ++nt)
#pragma unroll
                for (int r = 0; r < 4; ++r)
                    Ps[wid][l4 * 4 + r][nt * 16 + l15] = (_Float16)p[nt][r];
#pragma unroll
            for (int ht = 0; ht < 4; ++ht)
#pragma unroll
                for (int r = 0; r < 4; ++r) O[ht][r] *= sf[r];
            const f16x8 pf0 = *(const f16x8*)&Ps[wid][l15][l4 * 8];
            const f16x8 pf1 = *(const f16x8*)&Ps[wid][l15][32 + l4 * 8];
#pragma unroll
            for (int ht = 0; ht < 4; ++ht) {
                const f16x8 vf0 = *(const f16x8*)&Vs[ks][ht * 16 + l15][l4 * 8];
                const f16x8 vf1 = *(const f16x8*)&Vs[ks][ht * 16 + l15][32 + l4 * 8];
                O[ht] = __builtin_amdgcn_mfma_f32_16x16x32_f16(pf0, vf0, O[ht], 0, 0, 0);
                O[ht] = __builtin_amdgcn_mfma_f32_16x16x32_f16(pf1, vf1, O[ht], 0, 0, 0);
            }
        }
    }

    __syncthreads();
    const int row = l4 * 4;
    if (ks == 1) {
        if (l15 == 0) {
#pragma unroll
            for (int r = 0; r < 4; ++r) {
                Ml[qw][0][row + r] = m[r];
                Ml[qw][1][row + r] = l[r];
            }
        }
#pragma unroll
        for (int ht = 0; ht < 4; ++ht)
#pragma unroll
            for (int r = 0; r < 4; ++r)
                Om[qw][row + r][ht * 16 + l15] = O[ht][r];
    }
    __syncthreads();
    if (ks == 0) {
#pragma unroll
        for (int r = 0; r < 4; ++r) {
            const float m1 = Ml[qw][0][row + r];
            const float l1 = Ml[qw][1][row + r];
            const float mf = fmaxf(m[r], m1);
            const float a0 = __expf(m[r] - mf);
            const float a1 = __expf(m1 - mf);
            const float inv = 1.f / (l[r] * a0 + l1 * a1);
#pragma unroll
            for (int ht = 0; ht < 4; ++ht) {
                const float v =
                    (O[ht][r] * a0 + Om[qw][row + r][ht * 16 + l15] * a1) * inv;
                out[(bt0 + qb + qw * 16 + row + r) * H_ + ht * 16 + l15] = v;
            }
        }
    }
}

extern "C" void kernel_launch(void* const* d_in, const int* in_sizes, int n_in,
                              void* d_out, int out_size, void* d_ws, size_t ws_size,
                              hipStream_t stream) {
    const float* x  = (const float*)d_in[0];
    const float* Wk = (const float*)d_in[1];
    const float* Wq = (const float*)d_in[2];
    const float* Wv = (const float*)d_in[3];
    float* out = (float*)d_out;

    _Float16* qh = (_Float16*)d_ws;                  // [B*T][H] (scaled)
    _Float16* kh = qh + (size_t)B_ * T_ * H_;        // [B*T][H]
    _Float16* vt = kh + (size_t)B_ * T_ * H_;        // [H][B*T]
    _Float16* Wt = vt + (size_t)B_ * T_ * H_;        // [192][768]

    wt_cast<<<dim3(12), dim3(256), 0, stream>>>(Wk, Wq, Wv, Wt);
    qkv_gemm<<<dim3(512), dim3(256), 0, stream>>>(x, Wt, qh, kh, vt);
    attn<<<dim3(512), dim3(256), 0, stream>>>(qh, kh, vt, out);
}

// Round 4
// 86.516 us; speedup vs baseline: 10.1752x; 1.1954x over previous
//
#include <hip/hip_runtime.h>

typedef _Float16 f16x8 __attribute__((ext_vector_type(8)));
typedef _Float16 f16x4 __attribute__((ext_vector_type(4)));
typedef float    f32x4 __attribute__((ext_vector_type(4)));

#define B_ 4
#define T_ 4096
#define C_ 768
#define H_ 64
#define BT_ (B_ * T_)
#define SCALE 0.03608439182435161f   // 768^-0.5

// ---------------------------------------------------------------------------
// W transpose+cast: Wt f16 [192][768], rows 0-63 = Wq^T, 64-127 = Wk^T,
// 128-191 = Wv^T. 12 blocks x 256 threads, one 64-k slab each.
// ---------------------------------------------------------------------------
__global__ __launch_bounds__(256) void wt_cast(
    const float* __restrict__ Wk,
    const float* __restrict__ Wq,
    const float* __restrict__ Wv,
    _Float16* __restrict__ Wt)
{
    __shared__ float Ws[64][192];
    const int tid = threadIdx.x;
    const int k0  = blockIdx.x * 64;
    for (int i = tid; i < 64 * 64; i += 256) {
        const int r = i >> 6, c = i & 63;
        Ws[r][c]       = Wq[(size_t)(k0 + r) * H_ + c];
        Ws[r][64 + c]  = Wk[(size_t)(k0 + r) * H_ + c];
        Ws[r][128 + c] = Wv[(size_t)(k0 + r) * H_ + c];
    }
    __syncthreads();
#pragma unroll
    for (int r = 0; r < 6; ++r) {
        const int idx = tid + r * 256;
        const int n = idx >> 3, c8 = (idx & 7) * 8;
        f16x8 o;
#pragma unroll
        for (int j = 0; j < 8; ++j) o[j] = (_Float16)Ws[c8 + j][n];
        *(f16x8*)&Wt[(size_t)n * C_ + k0 + c8] = o;
    }
}

// ---------------------------------------------------------------------------
// QKV projection as MFMA GEMM: [16384 x 768] * [768 x 192]. (unchanged)
// ---------------------------------------------------------------------------
__global__ __launch_bounds__(256) void qkv_gemm(
    const float* __restrict__ x,
    const _Float16* __restrict__ Wt,
    _Float16* __restrict__ qh,
    _Float16* __restrict__ kh,
    _Float16* __restrict__ vt)
{
    __shared__ _Float16 Ah[32][72];
    __shared__ _Float16 Bh[192][72];

    const int tid  = threadIdx.x;
    const int lane = tid & 63;
    const int w    = tid >> 6;
    const int l15  = lane & 15;
    const int l4   = lane >> 4;
    const int mbase = blockIdx.x * 32;

    f32x4 acc[2][3];
#pragma unroll
    for (int mr = 0; mr < 2; ++mr)
#pragma unroll
        for (int j = 0; j < 3; ++j) acc[mr][j] = (f32x4){0.f, 0.f, 0.f, 0.f};

    for (int k0 = 0; k0 < C_; k0 += 64) {
        __syncthreads();
        {
            const int row = tid >> 3;
            const int cb  = (tid & 7) * 8;
            const float* src = &x[(size_t)(mbase + row) * C_ + k0 + cb];
#pragma unroll
            for (int i = 0; i < 2; ++i) {
                const float4 xv = *(const float4*)(src + i * 4);
                f16x4 h = { (_Float16)xv.x, (_Float16)xv.y,
                            (_Float16)xv.z, (_Float16)xv.w };
                *(f16x4*)&Ah[row][cb + i * 4] = h;
            }
        }
#pragma unroll
        for (int r = 0; r < 6; ++r) {
            const int idx = tid + r * 256;
            const int n = idx >> 3, c8 = (idx & 7) * 8;
            *(f16x8*)&Bh[n][c8] = *(const f16x8*)&Wt[(size_t)n * C_ + k0 + c8];
        }
        __syncthreads();
#pragma unroll
        for (int kk = 0; kk < 2; ++kk) {
            f16x8 af0 = *(const f16x8*)&Ah[l15][kk * 32 + l4 * 8];
            f16x8 af1 = *(const f16x8*)&Ah[16 + l15][kk * 32 + l4 * 8];
#pragma unroll
            for (int j = 0; j < 3; ++j) {
                const f16x8 bf =
                    *(const f16x8*)&Bh[w * 48 + j * 16 + l15][kk * 32 + l4 * 8];
                acc[0][j] = __builtin_amdgcn_mfma_f32_16x16x32_f16(af0, bf, acc[0][j], 0, 0, 0);
                acc[1][j] = __builtin_amdgcn_mfma_f32_16x16x32_f16(af1, bf, acc[1][j], 0, 0, 0);
            }
        }
    }

#pragma unroll
    for (int mr = 0; mr < 2; ++mr) {
        const size_t row0 = mbase + mr * 16 + l4 * 4;
#pragma unroll
        for (int j = 0; j < 3; ++j) {
            const int gcol = w * 48 + j * 16;
            if (gcol < 64) {
                const int h = gcol + l15;
#pragma unroll
                for (int r = 0; r < 4; ++r)
                    qh[(row0 + r) * H_ + h] = (_Float16)(acc[mr][j][r] * SCALE);
            } else if (gcol < 128) {
                const int h = gcol - 64 + l15;
#pragma unroll
                for (int r = 0; r < 4; ++r)
                    kh[(row0 + r) * H_ + h] = (_Float16)acc[mr][j][r];
            } else {
                const int h = gcol - 128 + l15;
                f16x4 o = { (_Float16)acc[mr][j][0], (_Float16)acc[mr][j][1],
                            (_Float16)acc[mr][j][2], (_Float16)acc[mr][j][3] };
                *(f16x4*)&vt[(size_t)h * BT_ + row0] = o;
            }
        }
    }
}

// ---------------------------------------------------------------------------
// Register-direct causal flash attention. No K/V LDS staging, no barriers in
// the main loop. Block = 4 waves, all on the SAME 32-row q-tile; causal kv
// range split round-robin across waves (wave w: tiles w, w+4, ...). K/V
// fragments loaded straight from global (L2-resident). 4-way merge in LDS.
// ---------------------------------------------------------------------------
__global__ __launch_bounds__(256, 2) void attn(
    const _Float16* __restrict__ qh,
    const _Float16* __restrict__ kh,
    const _Float16* __restrict__ vt,
    float* __restrict__ out)
{
    __shared__ _Float16 Ps[4][16][72];     // per-wave P layout shuffle
    __shared__ float    Om[3][2][16][68];  // partials of waves 1-3
    __shared__ float    Ml[3][2][2][16];   // m,l of waves 1-3

    const int b   = blockIdx.x >> 7;
    const int qt  = 127 - (blockIdx.x & 127);   // heavy first
    const int qb  = qt << 5;
    const int tid = threadIdx.x;
    const int lane = tid & 63;
    const int wid  = tid >> 6;                  // kv-quarter id
    const size_t bt0 = (size_t)b * T_;
    const int l15 = lane & 15;
    const int l4  = lane >> 4;

    // Q fragments for both 16-row subtiles (q pre-scaled)
    f16x8 qf[2][2];
#pragma unroll
    for (int qs = 0; qs < 2; ++qs) {
        const size_t qrow = bt0 + qb + qs * 16 + l15;
        qf[qs][0] = *(const f16x8*)&qh[qrow * H_ + l4 * 8];
        qf[qs][1] = *(const f16x8*)&qh[qrow * H_ + 32 + l4 * 8];
    }

    f32x4 O[2][4];
#pragma unroll
    for (int qs = 0; qs < 2; ++qs)
#pragma unroll
        for (int ht = 0; ht < 4; ++ht) O[qs][ht] = (f32x4){0.f, 0.f, 0.f, 0.f};
    float m[2][4], l[2][4];
#pragma unroll
    for (int qs = 0; qs < 2; ++qs)
#pragma unroll
        for (int r = 0; r < 4; ++r) { m[qs][r] = -1e30f; l[qs][r] = 0.f; }

    const int NT = (qb >> 6) + 1;
    for (int it = wid; it < NT; it += 4) {
        const int kb = it << 6;

        // ---- K fragments (B-operand): rows kb+nt*16+l15, h-halves
        f16x8 kf[4][2];
#pragma unroll
        for (int nt = 0; nt < 4; ++nt)
#pragma unroll
            for (int hf = 0; hf < 2; ++hf)
                kf[nt][hf] = *(const f16x8*)
                    &kh[(bt0 + kb + nt * 16 + l15) * H_ + hf * 32 + l4 * 8];
        // ---- V fragments (B-operand for PV): vt[h][s] rows
        f16x8 vf[4][2];
#pragma unroll
        for (int ht = 0; ht < 4; ++ht)
#pragma unroll
            for (int c = 0; c < 2; ++c)
                vf[ht][c] = *(const f16x8*)
                    &vt[(size_t)(ht * 16 + l15) * BT_ + bt0 + kb + c * 32 + l4 * 8];

        const bool needMask = (kb + 63 > qb);

#pragma unroll
        for (int qs = 0; qs < 2; ++qs) {
            // ---- S = Q K^T
            f32x4 sfr[4];
#pragma unroll
            for (int nt = 0; nt < 4; ++nt) {
                f32x4 z = (f32x4){0.f, 0.f, 0.f, 0.f};
                z = __builtin_amdgcn_mfma_f32_16x16x32_f16(qf[qs][0], kf[nt][0], z, 0, 0, 0);
                sfr[nt] = __builtin_amdgcn_mfma_f32_16x16x32_f16(qf[qs][1], kf[nt][1], z, 0, 0, 0);
            }
            // ---- causal mask (diagonal tile only)
            if (needMask) {
                const int qpos = qb + qs * 16 + l4 * 4;
#pragma unroll
                for (int nt = 0; nt < 4; ++nt) {
                    const int cpos = kb + nt * 16 + l15;
#pragma unroll
                    for (int r = 0; r < 4; ++r)
                        if (cpos > qpos + r) sfr[nt][r] = -1e30f;
                }
            }
            // ---- online softmax (rows across 16-lane groups)
            float sf[4];
            float p[4][4];
#pragma unroll
            for (int r = 0; r < 4; ++r) {
                float mx = fmaxf(fmaxf(sfr[0][r], sfr[1][r]),
                                 fmaxf(sfr[2][r], sfr[3][r]));
                mx = fmaxf(mx, __shfl_xor(mx, 1));
                mx = fmaxf(mx, __shfl_xor(mx, 2));
                mx = fmaxf(mx, __shfl_xor(mx, 4));
                mx = fmaxf(mx, __shfl_xor(mx, 8));
                const float mn = fmaxf(m[qs][r], mx);
                sf[r] = __expf(m[qs][r] - mn);
                float rs = 0.f;
#pragma unroll
                for (int nt = 0; nt < 4; ++nt) {
                    p[nt][r] = __expf(sfr[nt][r] - mn);
                    rs += p[nt][r];
                }
                rs += __shfl_xor(rs, 1);
                rs += __shfl_xor(rs, 2);
                rs += __shfl_xor(rs, 4);
                rs += __shfl_xor(rs, 8);
                l[qs][r] = l[qs][r] * sf[r] + rs;
                m[qs][r] = mn;
            }
            // ---- P: D-frag -> A-frag via per-wave LDS (no barrier needed)
#pragma unroll
            for (int nt = 0; nt < 4; ++nt)
#pragma unroll
                for (int r = 0; r < 4; ++r)
                    Ps[wid][l4 * 4 + r][nt * 16 + l15] = (_Float16)p[nt][r];
#pragma unroll
            for (int ht = 0; ht < 4; ++ht)
#pragma unroll
                for (int r = 0; r < 4; ++r) O[qs][ht][r] *= sf[r];
            const f16x8 pf0 = *(const f16x8*)&Ps[wid][l15][l4 * 8];
            const f16x8 pf1 = *(const f16x8*)&Ps[wid][l15][32 + l4 * 8];
            // ---- PV
#pragma unroll
            for (int ht = 0; ht < 4; ++ht) {
                O[qs][ht] = __builtin_amdgcn_mfma_f32_16x16x32_f16(pf0, vf[ht][0], O[qs][ht], 0, 0, 0);
                O[qs][ht] = __builtin_amdgcn_mfma_f32_16x16x32_f16(pf1, vf[ht][1], O[qs][ht], 0, 0, 0);
            }
        }
    }

    // ---- 4-way merge
    __syncthreads();
    if (wid != 0) {
#pragma unroll
        for (int qs = 0; qs < 2; ++qs) {
            if (l15 == 0) {
#pragma unroll
                for (int r = 0; r < 4; ++r) {
                    Ml[wid - 1][qs][0][l4 * 4 + r] = m[qs][r];
                    Ml[wid - 1][qs][1][l4 * 4 + r] = l[qs][r];
                }
            }
#pragma unroll
            for (int ht = 0; ht < 4; ++ht)
#pragma unroll
                for (int r = 0; r < 4; ++r)
                    Om[wid - 1][qs][l4 * 4 + r][ht * 16 + l15] = O[qs][ht][r];
        }
    }
    __syncthreads();
    if (wid == 0) {
#pragma unroll
        for (int qs = 0; qs < 2; ++qs) {
#pragma unroll
            for (int r = 0; r < 4; ++r) {
                const int row = l4 * 4 + r;
                float mf = m[qs][r];
#pragma unroll
                for (int i = 0; i < 3; ++i) mf = fmaxf(mf, Ml[i][qs][0][row]);
                const float a0 = __expf(m[qs][r] - mf);
                float ai[3];
                float denom = l[qs][r] * a0;
#pragma unroll
                for (int i = 0; i < 3; ++i) {
                    ai[i] = __expf(Ml[i][qs][0][row] - mf);
                    denom += Ml[i][qs][1][row] * ai[i];
                }
                const float inv = 1.f / denom;
#pragma unroll
                for (int ht = 0; ht < 4; ++ht) {
                    float val = O[qs][ht][r] * a0;
#pragma unroll
                    for (int i = 0; i < 3; ++i)
                        val += Om[i][qs][row][ht * 16 + l15] * ai[i];
                    out[(bt0 + qb + qs * 16 + row) * H_ + ht * 16 + l15] = val * inv;
                }
            }
        }
    }
}

extern "C" void kernel_launch(void* const* d_in, const int* in_sizes, int n_in,
                              void* d_out, int out_size, void* d_ws, size_t ws_size,
                              hipStream_t stream) {
    const float* x  = (const float*)d_in[0];
    const float* Wk = (const float*)d_in[1];
    const float* Wq = (const float*)d_in[2];
    const float* Wv = (const float*)d_in[3];
    float* out = (float*)d_out;

    _Float16* qh = (_Float16*)d_ws;                  // [B*T][H] (scaled)
    _Float16* kh = qh + (size_t)BT_ * H_;            // [B*T][H]
    _Float16* vt = kh + (size_t)BT_ * H_;            // [H][B*T]
    _Float16* Wt = vt + (size_t)BT_ * H_;            // [192][768]

    wt_cast<<<dim3(12), dim3(256), 0, stream>>>(Wk, Wq, Wv, Wt);
    qkv_gemm<<<dim3(512), dim3(256), 0, stream>>>(x, Wt, qh, kh, vt);
    attn<<<dim3(512), dim3(256), 0, stream>>>(qh, kh, vt, out);
}